// Round 1
// baseline (159.759 us; speedup 1.0000x reference)
//
#include <hip/hip_runtime.h>
#include <hip/hip_bf16.h>
#include <cstdint>
#include <cstddef>
#include <math.h>

#define B_SZ 512
#define E_SZ 512
#define C_SZ 70722
#define PAD_C 70784          // 553 * 128
#define M_MARGIN 0.4f
#define H_CONST 0.333f
#define S_CONST 64.0f
#define EPS_F 1e-3f
#define PI_F 3.14159265358979323846f

typedef __attribute__((ext_vector_type(8))) short short8;
typedef __attribute__((ext_vector_type(4))) float f32x4;

// ---------------- helpers ----------------

__device__ __forceinline__ unsigned short f2bf(float x) {
  __hip_bfloat16 h = __float2bfloat16(x);
  unsigned short u;
  __builtin_memcpy(&u, &h, 2);
  return u;
}

__device__ __forceinline__ void gload_lds16(const void* g, void* l) {
  __builtin_amdgcn_global_load_lds(
      (const __attribute__((address_space(1))) unsigned int*)g,
      (__attribute__((address_space(3))) unsigned int*)l, 16, 0, 0);
}

// XOR swizzle (byte form, bits 4-6): reads (c consecutive) ~2-way, writes (c stride 4) ~4-way
__device__ __forceinline__ int swzb(int rc) {
  return (((rc & 7) ^ ((rc >> 2) & 7)) << 4);
}

// ---------------- kernel 1: per-row margin stats ----------------
// 1 block x 512 threads. ga[i] = -M*ms_i ; gadd[i] = M + M*ms_i
__global__ void k_stats(const float* __restrict__ norms, const int* __restrict__ label,
                        float* __restrict__ ga, float* __restrict__ gadd) {
  __shared__ float sn[B_SZ];
  __shared__ int lab[B_SZ];
  __shared__ float redA[8], redB[8];
  __shared__ float sh_std;

  int t = threadIdx.x;
  float v = norms[t];
  v = fminf(fmaxf(v, 1e-3f), 100.0f);
  sn[t] = v;
  lab[t] = label[t];

  // wave (64-lane) reduce, then cross-wave
  float s1 = v, s2 = v * v;
  #pragma unroll
  for (int o = 32; o > 0; o >>= 1) {
    s1 += __shfl_down(s1, o);
    s2 += __shfl_down(s2, o);
  }
  if ((t & 63) == 0) { redA[t >> 6] = s1; redB[t >> 6] = s2; }
  __syncthreads();
  if (t == 0) {
    float a = 0.f, b = 0.f;
    #pragma unroll
    for (int i = 0; i < 8; ++i) { a += redA[i]; b += redB[i]; }
    float mean = a / (float)B_SZ;
    float var = (b - (float)B_SZ * mean * mean) / (float)(B_SZ - 1);
    sh_std = sqrtf(fmaxf(var, 0.f));
  }
  __syncthreads();
  float stdv = sh_std;

  int myl = lab[t];
  float s = 0.f, cnt = 0.f;
  for (int j = 0; j < B_SZ; ++j) {
    bool m = (lab[j] == myl);
    s += m ? sn[j] : 0.f;
    cnt += m ? 1.f : 0.f;
  }
  float gm = s / fmaxf(cnt, 1.f);   // count >= 1 always (self)
  float ms = (v - gm) / (stdv + EPS_F) * H_CONST;
  ms = fminf(fmaxf(ms, -1.f), 1.f);
  ga[t] = -M_MARGIN * ms;
  gadd[t] = M_MARGIN + M_MARGIN * ms;
}

// ---------------- kernel 2: emb fp32 -> bf16 ----------------
__global__ void k_cvtA(const float* __restrict__ emb, unsigned short* __restrict__ abf) {
  int i = (blockIdx.x * 256 + threadIdx.x) * 4;
  float4 f = *(const float4*)(emb + i);
  unsigned short u0 = f2bf(f.x), u1 = f2bf(f.y), u2 = f2bf(f.z), u3 = f2bf(f.w);
  unsigned long long pk = (unsigned long long)u0 | ((unsigned long long)u1 << 16) |
                          ((unsigned long long)u2 << 32) | ((unsigned long long)u3 << 48);
  *(unsigned long long*)(abf + i) = pk;
}

// ---------------- kernel 3: column inv-norms of kernel [E][C] ----------------
// block: 256 thr = 64 cols x 4 row-chunks. grid: ceil(C/64)=1106
__global__ void k_colnorm(const float* __restrict__ K, float* __restrict__ inv) {
  __shared__ float part[4][64];
  int cl = threadIdx.x & 63;
  int rq = threadIdx.x >> 6;
  int c = blockIdx.x * 64 + cl;
  float s = 0.f;
  if (c < C_SZ) {
    const float* p = K + (size_t)rq * 128 * C_SZ + c;
    #pragma unroll 8
    for (int r = 0; r < 128; ++r) {
      float x = p[(size_t)r * C_SZ];
      s += x * x;
    }
  }
  part[rq][cl] = s;
  __syncthreads();
  if (threadIdx.x < 64) {
    int c2 = blockIdx.x * 64 + threadIdx.x;
    if (c2 < C_SZ) {
      float tt = part[0][threadIdx.x] + part[1][threadIdx.x] +
                 part[2][threadIdx.x] + part[3][threadIdx.x];
      inv[c2] = rsqrtf(tt);
    } else if (c2 < PAD_C) {
      inv[c2] = 0.f;   // padded cols contribute zeros
    }
  }
}

// ---------------- kernel 4: GEMM + epilogue ----------------
// 128x128 tile, BK=64, 256 threads (4 waves, 2x2), 16x16x32 bf16 MFMA.
__launch_bounds__(256)
__global__ void k_gemm(const unsigned short* __restrict__ Abf,  // [512][512] bf16 bits
                       const float* __restrict__ Kmat,          // [512][C]
                       const float* __restrict__ invn,          // [PAD_C] padded
                       const int* __restrict__ label,
                       const float* __restrict__ ga,
                       const float* __restrict__ gadd,
                       float* __restrict__ out) {
  __shared__ __align__(16) unsigned short As[128 * 64];
  __shared__ __align__(16) unsigned short Bs[128 * 64];
  __shared__ int lab_s[128];
  __shared__ float ga_s[128], gadd_s[128];

  const int tid = threadIdx.x;
  const int nwg = gridDim.x;
  int bid = blockIdx.x;

  // bijective XCD swizzle (m204)
  int q = nwg >> 3, r8 = nwg & 7;
  int xcd = bid & 7, lb = bid >> 3;
  int wg = (xcd < r8 ? xcd * (q + 1) : r8 * (q + 1) + (xcd - r8) * q) + lb;

  const int mt = wg & 3;          // 4 M-tiles (M=512)
  const int nt = wg >> 2;         // 553 N-tiles
  const int row0 = mt << 7;
  const int col0 = nt << 7;

  if (tid < 128) {
    int gr = row0 + tid;
    lab_s[tid] = label[gr];
    ga_s[tid] = ga[gr];
    gadd_s[tid] = gadd[gr];
  }

  const int wid = tid >> 6, lane = tid & 63;
  const int wr = wid >> 1, wc = wid & 1;

  // B staging mapping: cc = 4-col chunk, kq base for 2-row chunks
  const int cc = tid & 31;
  const int kq = tid >> 5;

  const bool edge = (col0 + 128 > C_SZ);
  float4 inv4 = *(const float4*)(invn + col0 + cc * 4);  // padded, always safe

  f32x4 acc[4][4];
  #pragma unroll
  for (int m = 0; m < 4; ++m)
    #pragma unroll
    for (int n = 0; n < 4; ++n)
      acc[m][n] = f32x4{0.f, 0.f, 0.f, 0.f};

  const float* Bg = Kmat + col0;

  for (int kt = 0; kt < 8; ++kt) {
    const int kb = kt * 64;
    if (kt) __syncthreads();   // previous compute done before overwriting LDS

    // ---- stage A via global_load_lds, swizzle baked into per-lane global addr ----
    #pragma unroll
    for (int rr = 0; rr < 4; ++rr) {
      int rowblk = wid * 32 + rr * 8;              // wave-uniform
      int r = rowblk + (lane >> 3);
      int s = (lane & 7) ^ ((r & 7) ^ ((r >> 2) & 7));
      const unsigned short* g = Abf + (size_t)(row0 + r) * 512 + kb + s * 8;
      gload_lds16(g, (char*)As + rowblk * 128);
    }

    // ---- stage B: fp32 load, scale by inv_norm, bf16 pack, transposed LDS write ----
    #pragma unroll
    for (int i = 0; i < 4; ++i) {
      int k = (kq + i * 8) * 2;                    // 0..62 even
      const float* g0 = Bg + (size_t)(kb + k) * C_SZ + cc * 4;
      const float* g1 = g0 + C_SZ;
      float x0[4], x1[4];
      if (!edge) {
        float4 f0 = *(const float4*)g0;
        float4 f1 = *(const float4*)g1;
        x0[0] = f0.x; x0[1] = f0.y; x0[2] = f0.z; x0[3] = f0.w;
        x1[0] = f1.x; x1[1] = f1.y; x1[2] = f1.z; x1[3] = f1.w;
      } else {
        #pragma unroll
        for (int j = 0; j < 4; ++j) {
          int gc = col0 + cc * 4 + j;
          x0[j] = (gc < C_SZ) ? g0[j] : 0.f;
          x1[j] = (gc < C_SZ) ? g1[j] : 0.f;
        }
      }
      #pragma unroll
      for (int j = 0; j < 4; ++j) {
        int c = cc * 4 + j;
        float iv = ((const float*)&inv4)[j];
        unsigned int pk = ((unsigned int)f2bf(x1[j] * iv) << 16) | (unsigned int)f2bf(x0[j] * iv);
        int byte = (c * 128 + k * 2) ^ swzb(c);
        *(unsigned int*)((char*)Bs + byte) = pk;
      }
    }

    __syncthreads();

    // ---- compute: 2 k-substeps x 4x4 MFMA ----
    #pragma unroll
    for (int ks = 0; ks < 2; ++ks) {
      short8 a[4], b[4];
      #pragma unroll
      for (int m = 0; m < 4; ++m) {
        int row = wr * 64 + m * 16 + (lane & 15);
        int off = (row * 128 + ks * 64 + (lane >> 4) * 16) ^ swzb(row);
        a[m] = *(const short8*)((const char*)As + off);
      }
      #pragma unroll
      for (int n = 0; n < 4; ++n) {
        int c = wc * 64 + n * 16 + (lane & 15);
        int off = (c * 128 + ks * 64 + (lane >> 4) * 16) ^ swzb(c);
        b[n] = *(const short8*)((const char*)Bs + off);
      }
      #pragma unroll
      for (int m = 0; m < 4; ++m)
        #pragma unroll
        for (int n = 0; n < 4; ++n)
          acc[m][n] = __builtin_amdgcn_mfma_f32_16x16x32_bf16(a[m], b[n], acc[m][n], 0, 0, 0);
    }
  }

  // ---- epilogue ----
  #pragma unroll
  for (int m = 0; m < 4; ++m) {
    int rl0 = wr * 64 + m * 16 + ((lane >> 4) << 2);
    #pragma unroll
    for (int n = 0; n < 4; ++n) {
      int cl = wc * 64 + n * 16 + (lane & 15);
      int gc = col0 + cl;
      if (gc >= C_SZ) continue;
      #pragma unroll
      for (int r = 0; r < 4; ++r) {
        int rl = rl0 + r;
        float v = acc[m][n][r];
        v = fminf(fmaxf(v, -1.f + EPS_F), 1.f - EPS_F);
        float res = v * S_CONST;
        if (gc == lab_s[rl]) {
          float th = acosf(v) + ga_s[rl];
          th = fminf(fmaxf(th, EPS_F), PI_F - EPS_F);
          res = (cosf(th) - gadd_s[rl]) * S_CONST;
        }
        out[(size_t)(row0 + rl) * C_SZ + gc] = res;
      }
    }
  }
}

// ---------------- launch ----------------
extern "C" void kernel_launch(void* const* d_in, const int* in_sizes, int n_in,
                              void* d_out, int out_size, void* d_ws, size_t ws_size,
                              hipStream_t stream) {
  const float* emb   = (const float*)d_in[0];
  const float* norms = (const float*)d_in[1];
  const int*   label = (const int*)d_in[2];
  const float* kmat  = (const float*)d_in[3];
  float* out = (float*)d_out;

  // ws layout (16B-aligned carve):
  // [0, 283648)        inv_norm float[70912] (only [0,70784) used)
  // [283648, 285696)   ga float[512]
  // [285696, 287744)   gadd float[512]
  // [287744, 812032)   A bf16 [512*512]
  if (ws_size < 812032) return;
  char* ws = (char*)d_ws;
  float* invn = (float*)ws;
  float* ga   = (float*)(ws + 283648);
  float* gadd = (float*)(ws + 285696);
  unsigned short* abf = (unsigned short*)(ws + 287744);

  k_stats<<<1, 512, 0, stream>>>(norms, label, ga, gadd);
  k_cvtA<<<256, 256, 0, stream>>>(emb, abf);
  k_colnorm<<<1106, 256, 0, stream>>>(kmat, invn);
  k_gemm<<<2212, 256, 0, stream>>>(abf, kmat, invn, label, ga, gadd, out);
}

// Round 2
// 150.129 us; speedup vs baseline: 1.0641x; 1.0641x over previous
//
#include <hip/hip_runtime.h>
#include <hip/hip_bf16.h>
#include <cstdint>
#include <cstddef>
#include <math.h>

#define B_SZ 512
#define E_SZ 512
#define C_SZ 70722
#define PAD_C 70784          // 553 * 128
#define M_MARGIN 0.4f
#define H_CONST 0.333f
#define S_CONST 64.0f
#define EPS_F 1e-3f
#define PI_F 3.14159265358979323846f

typedef __attribute__((ext_vector_type(8))) short short8;
typedef __attribute__((ext_vector_type(4))) float f32x4;

// ---------------- helpers ----------------

__device__ __forceinline__ unsigned short f2bf(float x) {
  __hip_bfloat16 h = __float2bfloat16(x);
  unsigned short u;
  __builtin_memcpy(&u, &h, 2);
  return u;
}

__device__ __forceinline__ void gload_lds16(const void* g, void* l) {
  __builtin_amdgcn_global_load_lds(
      (const __attribute__((address_space(1))) unsigned int*)g,
      (__attribute__((address_space(3))) unsigned int*)l, 16, 0, 0);
}

// XOR swizzle (byte units, bits 4-6) for the 128B-row LDS tiles
__device__ __forceinline__ int swzb(int rc) {
  return (((rc & 7) ^ ((rc >> 2) & 7)) << 4);
}

// ---------------- kernel 1: per-row margin stats ----------------
__global__ void k_stats(const float* __restrict__ norms, const int* __restrict__ label,
                        float* __restrict__ ga, float* __restrict__ gadd) {
  __shared__ float sn[B_SZ];
  __shared__ int lab[B_SZ];
  __shared__ float redA[8], redB[8];
  __shared__ float sh_std;

  int t = threadIdx.x;
  float v = norms[t];
  v = fminf(fmaxf(v, 1e-3f), 100.0f);
  sn[t] = v;
  lab[t] = label[t];

  float s1 = v, s2 = v * v;
  #pragma unroll
  for (int o = 32; o > 0; o >>= 1) {
    s1 += __shfl_down(s1, o);
    s2 += __shfl_down(s2, o);
  }
  if ((t & 63) == 0) { redA[t >> 6] = s1; redB[t >> 6] = s2; }
  __syncthreads();
  if (t == 0) {
    float a = 0.f, b = 0.f;
    #pragma unroll
    for (int i = 0; i < 8; ++i) { a += redA[i]; b += redB[i]; }
    float mean = a / (float)B_SZ;
    float var = (b - (float)B_SZ * mean * mean) / (float)(B_SZ - 1);
    sh_std = sqrtf(fmaxf(var, 0.f));
  }
  __syncthreads();
  float stdv = sh_std;

  int myl = lab[t];
  float s = 0.f, cnt = 0.f;
  for (int j = 0; j < B_SZ; ++j) {
    bool m = (lab[j] == myl);
    s += m ? sn[j] : 0.f;
    cnt += m ? 1.f : 0.f;
  }
  float gm = s / fmaxf(cnt, 1.f);
  float ms = (v - gm) / (stdv + EPS_F) * H_CONST;
  ms = fminf(fmaxf(ms, -1.f), 1.f);
  ga[t] = -M_MARGIN * ms;
  gadd[t] = M_MARGIN + M_MARGIN * ms;
}

// ---------------- kernel 2: emb fp32 -> bf16 ----------------
__global__ void k_cvtA(const float* __restrict__ emb, unsigned short* __restrict__ abf) {
  int i = (blockIdx.x * 256 + threadIdx.x) * 4;
  float4 f = *(const float4*)(emb + i);
  unsigned short u0 = f2bf(f.x), u1 = f2bf(f.y), u2 = f2bf(f.z), u3 = f2bf(f.w);
  unsigned long long pk = (unsigned long long)u0 | ((unsigned long long)u1 << 16) |
                          ((unsigned long long)u2 << 32) | ((unsigned long long)u3 << 48);
  *(unsigned long long*)(abf + i) = pk;
}

// ---------------- kernel 3 (fast path): fused colnorm + transpose-convert ----------------
// 1106 blocks x 256 thr. Block owns 64 cols. Per 64k-chunk: coalesced fp32 read,
// sumsq accumulate, XOR-swizzled LDS fp32 transpose, bf16 pack, coalesced BT write.
// BT layout: [PAD_C][512] bf16 (unnormalized; invn applied in gemm epilogue).
__global__ void k_prep(const float* __restrict__ K, float* __restrict__ invn,
                       unsigned short* __restrict__ BT) {
  __shared__ float T[64 * 64];        // [k][c^((k&7)<<2)]
  __shared__ float part[16][64];

  const int t = threadIdx.x;
  const int c0 = blockIdx.x * 64;
  const int cl = t & 15;              // col-quad for load phase
  const int kr = t >> 4;              // 0..15
  const int cq = t >> 2;              // col for store phase (0..63)
  const int kq = t & 3;
  const bool full = (c0 + 64 <= C_SZ);

  float ss0 = 0.f, ss1 = 0.f, ss2 = 0.f, ss3 = 0.f;

  for (int ch = 0; ch < 8; ++ch) {
    if (ch) __syncthreads();          // previous store phase done before T overwrite
    #pragma unroll
    for (int i = 0; i < 4; ++i) {
      int klo = kr + i * 16;          // local k in tile
      int kg = ch * 64 + klo;
      float4 f;
      if (full) {
        f = *(const float4*)(K + (size_t)kg * C_SZ + c0 + cl * 4);
      } else {
        float* fp = (float*)&f;
        #pragma unroll
        for (int j = 0; j < 4; ++j) {
          int c = c0 + cl * 4 + j;
          fp[j] = (c < C_SZ) ? K[(size_t)kg * C_SZ + c] : 0.f;
        }
      }
      ss0 += f.x * f.x; ss1 += f.y * f.y; ss2 += f.z * f.z; ss3 += f.w * f.w;
      int swz = (klo & 7) << 2;
      *(float4*)&T[klo * 64 + ((cl * 4) ^ swz)] = f;
    }
    __syncthreads();
    // store phase: thread -> (col cq, 8 k's), two 16B stores per chunk
    #pragma unroll
    for (int sub = 0; sub < 2; ++sub) {
      int k8 = sub * 32 + kq * 8;     // k8 % 8 == 0 -> (k8+i)&7 == i
      short8 v;
      #pragma unroll
      for (int i = 0; i < 8; ++i) {
        v[i] = (short)f2bf(T[(k8 + i) * 64 + (cq ^ (i << 2))]);
      }
      *(short8*)(BT + ((size_t)(c0 + cq) << 9) + ch * 64 + k8) = v;
    }
  }

  __syncthreads();
  part[kr][cl * 4 + 0] = ss0;
  part[kr][cl * 4 + 1] = ss1;
  part[kr][cl * 4 + 2] = ss2;
  part[kr][cl * 4 + 3] = ss3;
  __syncthreads();
  if (t < 64) {
    int c = c0 + t;
    float s = 0.f;
    #pragma unroll
    for (int r = 0; r < 16; ++r) s += part[r][t];
    invn[c] = (c < C_SZ) ? rsqrtf(s) : 0.f;
  }
}

// ---------------- kernel 4 (fast path): GEMM + epilogue, both operands bf16 ----------------
__launch_bounds__(256)
__global__ void k_gemm_fast(const unsigned short* __restrict__ Abf,  // [512][512]
                            const unsigned short* __restrict__ BT,   // [PAD_C][512]
                            const float* __restrict__ invn,          // [PAD_C]
                            const int* __restrict__ label,
                            const float* __restrict__ ga,
                            const float* __restrict__ gadd,
                            float* __restrict__ out) {
  __shared__ __align__(16) unsigned short As[128 * 64];
  __shared__ __align__(16) unsigned short Bs[128 * 64];
  __shared__ int lab_s[128];
  __shared__ float ga_s[128], gadd_s[128];

  const int tid = threadIdx.x;
  const int nwg = gridDim.x;
  int bid = blockIdx.x;

  int q = nwg >> 3, r8 = nwg & 7;
  int xcd = bid & 7, lb = bid >> 3;
  int wg = (xcd < r8 ? xcd * (q + 1) : r8 * (q + 1) + (xcd - r8) * q) + lb;

  const int mt = wg & 3;
  const int nt = wg >> 2;
  const int row0 = mt << 7;
  const int col0 = nt << 7;

  if (tid < 128) {
    int gr = row0 + tid;
    lab_s[tid] = label[gr];
    ga_s[tid] = ga[gr];
    gadd_s[tid] = gadd[gr];
  }

  const int wid = tid >> 6, lane = tid & 63;
  const int wr = wid >> 1, wc = wid & 1;

  f32x4 acc[4][4];
  #pragma unroll
  for (int m = 0; m < 4; ++m)
    #pragma unroll
    for (int n = 0; n < 4; ++n)
      acc[m][n] = f32x4{0.f, 0.f, 0.f, 0.f};

  // precompute per-lane staging row/swizzle (shared by A and B)
  const int rsub = lane >> 3;
  const int lchunk = lane & 7;

  for (int kt = 0; kt < 8; ++kt) {
    const int kb = kt * 64;
    if (kt) __syncthreads();

    #pragma unroll
    for (int rr = 0; rr < 4; ++rr) {
      int rowblk = wid * 32 + rr * 8;            // wave-uniform LDS base
      int r = rowblk + rsub;
      int s = lchunk ^ ((r & 7) ^ ((r >> 2) & 7));
      gload_lds16(Abf + (size_t)(row0 + r) * 512 + kb + s * 8,
                  (char*)As + rowblk * 128);
      gload_lds16(BT + (size_t)(col0 + r) * 512 + kb + s * 8,
                  (char*)Bs + rowblk * 128);
    }

    __syncthreads();

    #pragma unroll
    for (int ks = 0; ks < 2; ++ks) {
      short8 a[4], b[4];
      #pragma unroll
      for (int m = 0; m < 4; ++m) {
        int row = wr * 64 + m * 16 + (lane & 15);
        int off = (row * 128 + ks * 64 + (lane >> 4) * 16) ^ swzb(row);
        a[m] = *(const short8*)((const char*)As + off);
      }
      #pragma unroll
      for (int n = 0; n < 4; ++n) {
        int c = wc * 64 + n * 16 + (lane & 15);
        int off = (c * 128 + ks * 64 + (lane >> 4) * 16) ^ swzb(c);
        b[n] = *(const short8*)((const char*)Bs + off);
      }
      #pragma unroll
      for (int m = 0; m < 4; ++m)
        #pragma unroll
        for (int n = 0; n < 4; ++n)
          acc[m][n] = __builtin_amdgcn_mfma_f32_16x16x32_bf16(a[m], b[n], acc[m][n], 0, 0, 0);
    }
  }

  // epilogue: scale by invn, clip, margin on label column
  float invc[4];
  #pragma unroll
  for (int n = 0; n < 4; ++n)
    invc[n] = invn[col0 + wc * 64 + n * 16 + (lane & 15)];

  #pragma unroll
  for (int m = 0; m < 4; ++m) {
    int rl0 = wr * 64 + m * 16 + ((lane >> 4) << 2);
    #pragma unroll
    for (int n = 0; n < 4; ++n) {
      int cl = wc * 64 + n * 16 + (lane & 15);
      int gc = col0 + cl;
      if (gc >= C_SZ) continue;
      #pragma unroll
      for (int r = 0; r < 4; ++r) {
        int rl = rl0 + r;
        float v = acc[m][n][r] * invc[n];
        v = fminf(fmaxf(v, -1.f + EPS_F), 1.f - EPS_F);
        float res = v * S_CONST;
        if (gc == lab_s[rl]) {
          float th = acosf(v) + ga_s[rl];
          th = fminf(fmaxf(th, EPS_F), PI_F - EPS_F);
          res = (cosf(th) - gadd_s[rl]) * S_CONST;
        }
        out[(size_t)(row0 + rl) * C_SZ + gc] = res;
      }
    }
  }
}

// ================= fallback path (round-1, known-good) =================

__global__ void k_colnorm(const float* __restrict__ K, float* __restrict__ inv) {
  __shared__ float part[4][64];
  int cl = threadIdx.x & 63;
  int rq = threadIdx.x >> 6;
  int c = blockIdx.x * 64 + cl;
  float s = 0.f;
  if (c < C_SZ) {
    const float* p = K + (size_t)rq * 128 * C_SZ + c;
    #pragma unroll 8
    for (int r = 0; r < 128; ++r) {
      float x = p[(size_t)r * C_SZ];
      s += x * x;
    }
  }
  part[rq][cl] = s;
  __syncthreads();
  if (threadIdx.x < 64) {
    int c2 = blockIdx.x * 64 + threadIdx.x;
    if (c2 < C_SZ) {
      float tt = part[0][threadIdx.x] + part[1][threadIdx.x] +
                 part[2][threadIdx.x] + part[3][threadIdx.x];
      inv[c2] = rsqrtf(tt);
    } else if (c2 < PAD_C) {
      inv[c2] = 0.f;
    }
  }
}

__launch_bounds__(256)
__global__ void k_gemm_fb(const unsigned short* __restrict__ Abf,
                          const float* __restrict__ Kmat,
                          const float* __restrict__ invn,
                          const int* __restrict__ label,
                          const float* __restrict__ ga,
                          const float* __restrict__ gadd,
                          float* __restrict__ out) {
  __shared__ __align__(16) unsigned short As[128 * 64];
  __shared__ __align__(16) unsigned short Bs[128 * 64];
  __shared__ int lab_s[128];
  __shared__ float ga_s[128], gadd_s[128];

  const int tid = threadIdx.x;
  const int nwg = gridDim.x;
  int bid = blockIdx.x;
  int q = nwg >> 3, r8 = nwg & 7;
  int xcd = bid & 7, lb = bid >> 3;
  int wg = (xcd < r8 ? xcd * (q + 1) : r8 * (q + 1) + (xcd - r8) * q) + lb;
  const int mt = wg & 3;
  const int nt = wg >> 2;
  const int row0 = mt << 7;
  const int col0 = nt << 7;

  if (tid < 128) {
    int gr = row0 + tid;
    lab_s[tid] = label[gr];
    ga_s[tid] = ga[gr];
    gadd_s[tid] = gadd[gr];
  }

  const int wid = tid >> 6, lane = tid & 63;
  const int wr = wid >> 1, wc = wid & 1;
  const int cc = tid & 31;
  const int kq = tid >> 5;
  const bool edge = (col0 + 128 > C_SZ);
  float4 inv4 = *(const float4*)(invn + col0 + cc * 4);

  f32x4 acc[4][4];
  #pragma unroll
  for (int m = 0; m < 4; ++m)
    #pragma unroll
    for (int n = 0; n < 4; ++n)
      acc[m][n] = f32x4{0.f, 0.f, 0.f, 0.f};

  const float* Bg = Kmat + col0;

  for (int kt = 0; kt < 8; ++kt) {
    const int kb = kt * 64;
    if (kt) __syncthreads();

    #pragma unroll
    for (int rr = 0; rr < 4; ++rr) {
      int rowblk = wid * 32 + rr * 8;
      int r = rowblk + (lane >> 3);
      int s = (lane & 7) ^ ((r & 7) ^ ((r >> 2) & 7));
      gload_lds16(Abf + (size_t)(row0 + r) * 512 + kb + s * 8, (char*)As + rowblk * 128);
    }

    #pragma unroll
    for (int i = 0; i < 4; ++i) {
      int k = (kq + i * 8) * 2;
      const float* g0 = Bg + (size_t)(kb + k) * C_SZ + cc * 4;
      const float* g1 = g0 + C_SZ;
      float x0[4], x1[4];
      if (!edge) {
        float4 f0 = *(const float4*)g0;
        float4 f1 = *(const float4*)g1;
        x0[0]=f0.x; x0[1]=f0.y; x0[2]=f0.z; x0[3]=f0.w;
        x1[0]=f1.x; x1[1]=f1.y; x1[2]=f1.z; x1[3]=f1.w;
      } else {
        #pragma unroll
        for (int j = 0; j < 4; ++j) {
          int gc = col0 + cc * 4 + j;
          x0[j] = (gc < C_SZ) ? g0[j] : 0.f;
          x1[j] = (gc < C_SZ) ? g1[j] : 0.f;
        }
      }
      #pragma unroll
      for (int j = 0; j < 4; ++j) {
        int c = cc * 4 + j;
        float iv = ((const float*)&inv4)[j];
        unsigned int pk = ((unsigned int)f2bf(x1[j] * iv) << 16) | (unsigned int)f2bf(x0[j] * iv);
        int byte = (c * 128 + k * 2) ^ swzb(c);
        *(unsigned int*)((char*)Bs + byte) = pk;
      }
    }

    __syncthreads();

    #pragma unroll
    for (int ks = 0; ks < 2; ++ks) {
      short8 a[4], b[4];
      #pragma unroll
      for (int m = 0; m < 4; ++m) {
        int row = wr * 64 + m * 16 + (lane & 15);
        int off = (row * 128 + ks * 64 + (lane >> 4) * 16) ^ swzb(row);
        a[m] = *(const short8*)((const char*)As + off);
      }
      #pragma unroll
      for (int n = 0; n < 4; ++n) {
        int c = wc * 64 + n * 16 + (lane & 15);
        int off = (c * 128 + ks * 64 + (lane >> 4) * 16) ^ swzb(c);
        b[n] = *(const short8*)((const char*)Bs + off);
      }
      #pragma unroll
      for (int m = 0; m < 4; ++m)
        #pragma unroll
        for (int n = 0; n < 4; ++n)
          acc[m][n] = __builtin_amdgcn_mfma_f32_16x16x32_bf16(a[m], b[n], acc[m][n], 0, 0, 0);
    }
  }

  #pragma unroll
  for (int m = 0; m < 4; ++m) {
    int rl0 = wr * 64 + m * 16 + ((lane >> 4) << 2);
    #pragma unroll
    for (int n = 0; n < 4; ++n) {
      int cl = wc * 64 + n * 16 + (lane & 15);
      int gc = col0 + cl;
      if (gc >= C_SZ) continue;
      #pragma unroll
      for (int r = 0; r < 4; ++r) {
        int rl = rl0 + r;
        float v = acc[m][n][r];
        v = fminf(fmaxf(v, -1.f + EPS_F), 1.f - EPS_F);
        float res = v * S_CONST;
        if (gc == lab_s[rl]) {
          float th = acosf(v) + ga_s[rl];
          th = fminf(fmaxf(th, EPS_F), PI_F - EPS_F);
          res = (cosf(th) - gadd_s[rl]) * S_CONST;
        }
        out[(size_t)(row0 + rl) * C_SZ + gc] = res;
      }
    }
  }
}

// ---------------- launch ----------------
extern "C" void kernel_launch(void* const* d_in, const int* in_sizes, int n_in,
                              void* d_out, int out_size, void* d_ws, size_t ws_size,
                              hipStream_t stream) {
  const float* emb   = (const float*)d_in[0];
  const float* norms = (const float*)d_in[1];
  const int*   label = (const int*)d_in[2];
  const float* kmat  = (const float*)d_in[3];
  float* out = (float*)d_out;

  // fast-path ws layout:
  //   [0, 283136)          invn  float[PAD_C]
  //   [283136, 285184)     ga    float[512]
  //   [285184, 287232)     gadd  float[512]
  //   [287232, 811520)     Abf   bf16[512*512]
  //   [811520, 73294336)   BT    bf16[PAD_C][512]
  const size_t NEED_FAST = 73294336;
  char* ws = (char*)d_ws;
  float* invn = (float*)ws;
  float* ga   = (float*)(ws + 283136);
  float* gadd = (float*)(ws + 285184);
  unsigned short* abf = (unsigned short*)(ws + 287232);
  unsigned short* bt  = (unsigned short*)(ws + 811520);

  k_stats<<<1, 512, 0, stream>>>(norms, label, ga, gadd);
  k_cvtA<<<256, 256, 0, stream>>>(emb, abf);

  if (ws_size >= NEED_FAST) {
    k_prep<<<1106, 256, 0, stream>>>(kmat, invn, bt);
    k_gemm_fast<<<2212, 256, 0, stream>>>(abf, bt, invn, label, ga, gadd, out);
  } else {
    k_colnorm<<<1106, 256, 0, stream>>>(kmat, invn);
    k_gemm_fb<<<2212, 256, 0, stream>>>(abf, kmat, invn, label, ga, gadd, out);
  }
}